// Round 11
// baseline (114.273 us; speedup 1.0000x reference)
//
#include <hip/hip_runtime.h>

// PositionLinear + ReLU via MFMA: out[t,:] = relu(W @ x[t,:] + b)
// x: [1M][64] f32, W: [64][64] f32, b: [64], out: [1M][64] f32.
// HBM floor ~536 MB @ ~6.3 TB/s => ~85 us. Round 10 (this structure, cached
// accesses) = 107.4 us = 5.0 TB/s effective (79% of copy ceiling), with ~90%
// issue slack -> memory-system bound, not compute/latency bound.
//
// Round 11 = round 10 + NON-TEMPORAL x loads / out stores (single change).
// Both streams are touch-once; letting them allocate in L1/L2 evicts 536 MB
// of dead lines through 4 MB/XCD L2 per pass. __builtin_nontemporal_* emits
// nt-flagged vmem (streaming, no-allocate) -> saves L2 evict/tag overhead.
// W/bias stay cached (hot, reused by all waves).
//
// Math (unchanged): x = xh+xl, W = Wh+Wl (RN f16 pairs);
// x.w ~= Ah*Bh + Ah*Bl + Al*Bh; products exact in f32, f32 accum ->
// fp32-level accuracy (absmax 0.015625, same as the fp32-VALU kernels).
//
// Fragment layouts (16x16x32, C/D verified m89):
//   A (16x32): row m = lane&15, k = (lane>>4)*8 + j (+32 for k-half 1)
//   B (32x16): col n = lane&15, same k mapping
//   D (16x16): col n = lane&15, row m = (lane>>4)*4 + reg
// Persistent grid 768x4 waves (12 waves/CU); W fragments in regs once;
// x prefetch depth 1 (register dbuf). No LDS, no barriers.

typedef _Float16 half8   __attribute__((ext_vector_type(8)));
typedef float    floatx4 __attribute__((ext_vector_type(4)));

#define NDIM   64
#define TOKENS (1u << 20)
#define TILES  (TOKENS / 16)        // 65536 tiles of 16 tokens
#define NBLK   768
#define WPB    4
#define NWAVES (NBLK * WPB)         // 3072

__device__ __forceinline__ void split8(const float v[8], half8& hi, half8& lo) {
#pragma unroll
    for (int j = 0; j < 8; ++j) {
        const _Float16 h = (_Float16)v[j];
        hi[j] = h;
        lo[j] = (_Float16)(v[j] - (float)h);   // exact residual
    }
}

struct Frag {
    half8 Bh[4][2], Bl[4][2];
    float bv[4];
};

__device__ __forceinline__ void loadx(floatx4 (&b)[4], const float* __restrict__ x,
                                      unsigned ti, int fr, int kg) {
    const floatx4* xp = reinterpret_cast<const floatx4*>(
        x + ((size_t)ti * 16 + fr) * NDIM + kg * 8);
    b[0] = __builtin_nontemporal_load(xp);       // +0 floats
    b[1] = __builtin_nontemporal_load(xp + 1);   // +4
    b[2] = __builtin_nontemporal_load(xp + 8);   // +32
    b[3] = __builtin_nontemporal_load(xp + 9);   // +36
}

__device__ __forceinline__ void body(const floatx4 (&b)[4], const Frag& f,
                                     float* __restrict__ out, unsigned ti,
                                     int fr, int kg) {
    const float cva[8] = {b[0].x, b[0].y, b[0].z, b[0].w,
                          b[1].x, b[1].y, b[1].z, b[1].w};
    const float cvb[8] = {b[2].x, b[2].y, b[2].z, b[2].w,
                          b[3].x, b[3].y, b[3].z, b[3].w};
    half8 Ah0, Al0, Ah1, Al1;
    split8(cva, Ah0, Al0);
    split8(cvb, Ah1, Al1);

    floatx4 acc[4];
#pragma unroll
    for (int nt = 0; nt < 4; ++nt)
        acc[nt] = (floatx4){f.bv[nt], f.bv[nt], f.bv[nt], f.bv[nt]};
#pragma unroll
    for (int nt = 0; nt < 4; ++nt) {
        acc[nt] = __builtin_amdgcn_mfma_f32_16x16x32_f16(Ah0, f.Bl[nt][0], acc[nt], 0, 0, 0);
        acc[nt] = __builtin_amdgcn_mfma_f32_16x16x32_f16(Al0, f.Bh[nt][0], acc[nt], 0, 0, 0);
        acc[nt] = __builtin_amdgcn_mfma_f32_16x16x32_f16(Ah0, f.Bh[nt][0], acc[nt], 0, 0, 0);
        acc[nt] = __builtin_amdgcn_mfma_f32_16x16x32_f16(Ah1, f.Bl[nt][1], acc[nt], 0, 0, 0);
        acc[nt] = __builtin_amdgcn_mfma_f32_16x16x32_f16(Al1, f.Bh[nt][1], acc[nt], 0, 0, 0);
        acc[nt] = __builtin_amdgcn_mfma_f32_16x16x32_f16(Ah1, f.Bh[nt][1], acc[nt], 0, 0, 0);
    }

    // D: col n = fr, row m = kg*4 + j. Per (j): the 4 nt-stores are adjacent
    // in program order -> each 256B output row completes within 4 instrs.
    float* op = out + ((size_t)ti * 16 + kg * 4) * NDIM + fr;
#pragma unroll
    for (int j = 0; j < 4; ++j) {
#pragma unroll
        for (int nt = 0; nt < 4; ++nt)
            __builtin_nontemporal_store(fmaxf(acc[nt][j], 0.0f),
                                        op + j * NDIM + nt * 16);
    }
}

__global__
__attribute__((amdgpu_flat_work_group_size(256, 256), amdgpu_waves_per_eu(2, 3)))
void poslin_relu_mfma(const float* __restrict__ x,
                      const float* __restrict__ W,
                      const float* __restrict__ bias,
                      float* __restrict__ out)
{
    const int tid  = threadIdx.x;
    const int wv   = tid >> 6;
    const int lane = tid & 63;
    const int fr   = lane & 15;   // free-dim index (m for A, n for B/D)
    const int kg   = lane >> 4;   // k base = kg*8 (+32 per k-half)

    // ---- B fragments: W^T -> registers once, hi/lo f16 split (cached) ----
    Frag f;
#pragma unroll
    for (int nt = 0; nt < 4; ++nt) {
#pragma unroll
        for (int kh = 0; kh < 2; ++kh) {
            const float* wp = W + (size_t)(nt * 16 + fr) * NDIM + kg * 8 + kh * 32;
            const float4 a = *reinterpret_cast<const float4*>(wp);
            const float4 c = *reinterpret_cast<const float4*>(wp + 4);
            const float tmp[8] = {a.x, a.y, a.z, a.w, c.x, c.y, c.z, c.w};
            split8(tmp, f.Bh[nt][kh], f.Bl[nt][kh]);
        }
    }
#pragma unroll
    for (int nt = 0; nt < 4; ++nt) f.bv[nt] = bias[nt * 16 + fr];

    // ---- persistent tile stream, register double-buffer, prefetch 1 ----
    floatx4 xa[4], xb[4];
    unsigned t = (unsigned)blockIdx.x * WPB + wv;
    if (t >= TILES) return;
    loadx(xa, x, t, fr, kg);
    while (true) {
        const unsigned tn = t + NWAVES;
        if (tn < TILES) loadx(xb, x, tn, fr, kg);
        body(xa, f, out, t, fr, kg);
        if (tn >= TILES) break;
        t = tn;
        const unsigned tm = t + NWAVES;
        if (tm < TILES) loadx(xa, x, tm, fr, kg);
        body(xb, f, out, t, fr, kg);
        if (tm >= TILES) break;
        t = tm;
    }
}

extern "C" void kernel_launch(void* const* d_in, const int* in_sizes, int n_in,
                              void* d_out, int out_size, void* d_ws, size_t ws_size,
                              hipStream_t stream) {
    const float* x    = (const float*)d_in[0];
    const float* W    = (const float*)d_in[1];
    const float* bias = (const float*)d_in[2];
    float* out        = (float*)d_out;

    poslin_relu_mfma<<<NBLK, 256, 0, stream>>>(x, W, bias, out);
}

// Round 12
// 107.333 us; speedup vs baseline: 1.0647x; 1.0647x over previous
//
#include <hip/hip_runtime.h>

// PositionLinear + ReLU via MFMA: out[t,:] = relu(W @ x[t,:] + b)
// x: [1M][64] f32, W: [64][64] f32, b: [64], out: [1M][64] f32.
//
// FINAL (round 12 = exact revert to round 10, the best measured variant:
// 107.4 us). Round 11's nontemporal experiment REGRESSED (114.3 us): the
// cached path's L2/MALL write-combining beats no-allocate streaming for
// this 1:1 R/W mix. That rejection closes the last residual hypothesis:
//   - compulsory traffic 536 MB; 107.4 us => 5.0 TB/s sustained mixed R/W
//     (79% of 6.3 TB/s pure-copy ceiling; pure-write fillBuffer measures
//     ~7.0 TB/s on the same chip/session).
//   - issue-side slack ~90% (24 MFMA + ~100 VALU per 16-token tile);
//     prefetch keeps 5x the in-flight bytes needed for latency hiding.
// => DRAM read/write-turnaround efficiency is the binding constraint;
//    not addressable from HIP source. ROOFLINE.
//
// Math: x = xh + xl (RN f16 pair), W = Wh + Wl; x.w ~= Ah*Bh + Ah*Bl + Al*Bh
// (dropped Al*Bl <= 2^-22 |x.w|); products exact in f32, f32 accumulation ->
// fp32-level accuracy (absmax 0.015625, identical to the fp32-VALU kernels).
//
// Fragment layouts (16x16x32, C/D verified m89):
//   A (16x32): row m = lane&15, k = (lane>>4)*8 + j (+32 for k-half 1)
//   B (32x16): col n = lane&15, same k mapping
//   D (16x16): col n = lane&15, row m = (lane>>4)*4 + reg
// B = W^T: lane reads W row (nt*16 + lane&15), 8 consecutive floats per
// k-half. Persistent grid 768x4 waves (12 waves/CU); W fragments built once
// per wave; x prefetch depth 1 in registers. No LDS, no barriers.

typedef _Float16 half8   __attribute__((ext_vector_type(8)));
typedef float    floatx4 __attribute__((ext_vector_type(4)));

#define NDIM   64
#define TOKENS (1u << 20)
#define TILES  (TOKENS / 16)        // 65536 tiles of 16 tokens
#define NBLK   768
#define WPB    4
#define NWAVES (NBLK * WPB)         // 3072

__device__ __forceinline__ void split8(const float v[8], half8& hi, half8& lo) {
#pragma unroll
    for (int j = 0; j < 8; ++j) {
        const _Float16 h = (_Float16)v[j];
        hi[j] = h;
        lo[j] = (_Float16)(v[j] - (float)h);   // exact residual
    }
}

struct Frag {
    half8 Bh[4][2], Bl[4][2];
    float bv[4];
};

__device__ __forceinline__ void loadx(float4 (&b)[4], const float* __restrict__ x,
                                      unsigned ti, int fr, int kg) {
    const float* xp = x + ((size_t)ti * 16 + fr) * NDIM + kg * 8;
    b[0] = *reinterpret_cast<const float4*>(xp);
    b[1] = *reinterpret_cast<const float4*>(xp + 4);
    b[2] = *reinterpret_cast<const float4*>(xp + 32);
    b[3] = *reinterpret_cast<const float4*>(xp + 36);
}

__device__ __forceinline__ void body(const float4 (&b)[4], const Frag& f,
                                     float* __restrict__ out, unsigned ti,
                                     int fr, int kg) {
    const float cva[8] = {b[0].x, b[0].y, b[0].z, b[0].w,
                          b[1].x, b[1].y, b[1].z, b[1].w};
    const float cvb[8] = {b[2].x, b[2].y, b[2].z, b[2].w,
                          b[3].x, b[3].y, b[3].z, b[3].w};
    half8 Ah0, Al0, Ah1, Al1;
    split8(cva, Ah0, Al0);
    split8(cvb, Ah1, Al1);

    floatx4 acc[4];
#pragma unroll
    for (int nt = 0; nt < 4; ++nt)
        acc[nt] = (floatx4){f.bv[nt], f.bv[nt], f.bv[nt], f.bv[nt]};
#pragma unroll
    for (int nt = 0; nt < 4; ++nt) {
        acc[nt] = __builtin_amdgcn_mfma_f32_16x16x32_f16(Ah0, f.Bl[nt][0], acc[nt], 0, 0, 0);
        acc[nt] = __builtin_amdgcn_mfma_f32_16x16x32_f16(Al0, f.Bh[nt][0], acc[nt], 0, 0, 0);
        acc[nt] = __builtin_amdgcn_mfma_f32_16x16x32_f16(Ah0, f.Bh[nt][0], acc[nt], 0, 0, 0);
        acc[nt] = __builtin_amdgcn_mfma_f32_16x16x32_f16(Ah1, f.Bl[nt][1], acc[nt], 0, 0, 0);
        acc[nt] = __builtin_amdgcn_mfma_f32_16x16x32_f16(Al1, f.Bh[nt][1], acc[nt], 0, 0, 0);
        acc[nt] = __builtin_amdgcn_mfma_f32_16x16x32_f16(Ah1, f.Bh[nt][1], acc[nt], 0, 0, 0);
    }

    // D: col n = fr, row m = kg*4 + j. Four lanes with the same fr write 4
    // consecutive rows; per (j, nt) a wave's 16 fr-lanes write 64B runs.
    float* op = out + ((size_t)ti * 16 + kg * 4) * NDIM + fr;
#pragma unroll
    for (int j = 0; j < 4; ++j) {
#pragma unroll
        for (int nt = 0; nt < 4; ++nt)
            op[j * NDIM + nt * 16] = fmaxf(acc[nt][j], 0.0f);
    }
}

__global__
__attribute__((amdgpu_flat_work_group_size(256, 256), amdgpu_waves_per_eu(2, 3)))
void poslin_relu_mfma(const float* __restrict__ x,
                      const float* __restrict__ W,
                      const float* __restrict__ bias,
                      float* __restrict__ out)
{
    const int tid  = threadIdx.x;
    const int wv   = tid >> 6;
    const int lane = tid & 63;
    const int fr   = lane & 15;   // free-dim index (m for A, n for B/D)
    const int kg   = lane >> 4;   // k base = kg*8 (+32 per k-half)

    // ---- B fragments: W^T -> registers once, hi/lo f16 split ----
    Frag f;
#pragma unroll
    for (int nt = 0; nt < 4; ++nt) {
#pragma unroll
        for (int kh = 0; kh < 2; ++kh) {
            const float* wp = W + (size_t)(nt * 16 + fr) * NDIM + kg * 8 + kh * 32;
            const float4 a = *reinterpret_cast<const float4*>(wp);
            const float4 c = *reinterpret_cast<const float4*>(wp + 4);
            const float tmp[8] = {a.x, a.y, a.z, a.w, c.x, c.y, c.z, c.w};
            split8(tmp, f.Bh[nt][kh], f.Bl[nt][kh]);
        }
    }
#pragma unroll
    for (int nt = 0; nt < 4; ++nt) f.bv[nt] = bias[nt * 16 + fr];

    // ---- persistent tile stream, register double-buffer, prefetch 1 ----
    float4 xa[4], xb[4];
    unsigned t = (unsigned)blockIdx.x * WPB + wv;
    if (t >= TILES) return;
    loadx(xa, x, t, fr, kg);
    while (true) {
        const unsigned tn = t + NWAVES;
        if (tn < TILES) loadx(xb, x, tn, fr, kg);
        body(xa, f, out, t, fr, kg);
        if (tn >= TILES) break;
        t = tn;
        const unsigned tm = t + NWAVES;
        if (tm < TILES) loadx(xa, x, tm, fr, kg);
        body(xb, f, out, t, fr, kg);
        if (tm >= TILES) break;
        t = tm;
    }
}

extern "C" void kernel_launch(void* const* d_in, const int* in_sizes, int n_in,
                              void* d_out, int out_size, void* d_ws, size_t ws_size,
                              hipStream_t stream) {
    const float* x    = (const float*)d_in[0];
    const float* W    = (const float*)d_in[1];
    const float* bias = (const float*)d_in[2];
    float* out        = (float*)d_out;

    poslin_relu_mfma<<<NBLK, 256, 0, stream>>>(x, W, bias, out);
}